// Round 6
// baseline (219.836 us; speedup 1.0000x reference)
//
#include <hip/hip_runtime.h>
#include <hip/hip_bf16.h>

#define NN    50000
#define EE    1600000
#define IND   128
#define OUTD  64
#define SLOPE 0.1f

#define BSH    5                   // log2(nodes per bucket)
#define BW     32                  // nodes per bucket (src >> 5)
#define NB     1564                // ceil(NN / 32)
#define CAP    1408                // mean 1024 + 12 sigma (fixed input, key=0)
#define CAPT   6                   // ceil(CAP/256) register stash bound
#define NBLK   1000
#define CHUNK  (EE / NBLK)         // 1600 edges per binscatter block

// ---------------------------------------------------------------------------
// K1: new = x @ W.T + b  (fp32 vector ALU; no fp32 MFMA on CDNA4)
//     nbuf stored bf16 (row = 128B); s_src/s_dst fp32.
// ---------------------------------------------------------------------------
__global__ __launch_bounds__(256) void linear_kernel(
    const float* __restrict__ x, const float* __restrict__ W,
    const float* __restrict__ bias, const float* __restrict__ a,
    ushort* __restrict__ nbuf2, float* __restrict__ s_src, float* __restrict__ s_dst)
{
    __shared__ float Wt[IND][OUTD + 4];   // Wt[k][j] = W[j*128+k]
    __shared__ float xs[16][IND + 4];
    const int tid = threadIdx.x;

    #pragma unroll
    for (int i = 0; i < 32; ++i) {
        int idx = tid + i * 256;          // coalesced global read of W
        Wt[idx & 127][idx >> 7] = W[idx];
    }
    const int node0 = blockIdx.x * 16;
    const float4* x4 = (const float4*)(x + (size_t)node0 * IND);
    #pragma unroll
    for (int i = 0; i < 2; ++i) {
        int idx = tid + i * 256;          // 512 float4 = 16 rows x 32
        int row = idx >> 5, col = (idx & 31) * 4;
        *(float4*)&xs[row][col] = x4[idx];
    }
    __syncthreads();

    const int nl = tid >> 4;              // local node 0..15
    const int jg = tid & 15;              // dim group
    const int j0 = jg * 4;
    float4 acc = *(const float4*)&bias[j0];
    const float* xrow = xs[nl];
    #pragma unroll
    for (int k = 0; k < IND; k += 4) {
        float4 xv = *(const float4*)&xrow[k];
        float4 w0 = *(const float4*)&Wt[k + 0][j0];
        float4 w1 = *(const float4*)&Wt[k + 1][j0];
        float4 w2 = *(const float4*)&Wt[k + 2][j0];
        float4 w3 = *(const float4*)&Wt[k + 3][j0];
        acc.x = fmaf(xv.x, w0.x, acc.x); acc.y = fmaf(xv.x, w0.y, acc.y);
        acc.z = fmaf(xv.x, w0.z, acc.z); acc.w = fmaf(xv.x, w0.w, acc.w);
        acc.x = fmaf(xv.y, w1.x, acc.x); acc.y = fmaf(xv.y, w1.y, acc.y);
        acc.z = fmaf(xv.y, w1.z, acc.z); acc.w = fmaf(xv.y, w1.w, acc.w);
        acc.x = fmaf(xv.z, w2.x, acc.x); acc.y = fmaf(xv.z, w2.y, acc.y);
        acc.z = fmaf(xv.z, w2.z, acc.z); acc.w = fmaf(xv.z, w2.w, acc.w);
        acc.x = fmaf(xv.w, w3.x, acc.x); acc.y = fmaf(xv.w, w3.y, acc.y);
        acc.z = fmaf(xv.w, w3.z, acc.z); acc.w = fmaf(xv.w, w3.w, acc.w);
    }
    const int n = node0 + nl;
    ushort4 pk;
    { __hip_bfloat16 h;
      h = __float2bfloat16(acc.x); pk.x = *(ushort*)&h;
      h = __float2bfloat16(acc.y); pk.y = *(ushort*)&h;
      h = __float2bfloat16(acc.z); pk.z = *(ushort*)&h;
      h = __float2bfloat16(acc.w); pk.w = *(ushort*)&h; }
    *(ushort4*)&nbuf2[(size_t)n * OUTD + j0] = pk;

    float ss = acc.x * a[j0]        + acc.y * a[j0 + 1]
             + acc.z * a[j0 + 2]    + acc.w * a[j0 + 3];
    float sd = acc.x * a[OUTD + j0]     + acc.y * a[OUTD + j0 + 1]
             + acc.z * a[OUTD + j0 + 2] + acc.w * a[OUTD + j0 + 3];
    #pragma unroll
    for (int m = 1; m < 16; m <<= 1) {
        ss += __shfl_xor(ss, m, 64);
        sd += __shfl_xor(sd, m, 64);
    }
    if (jg == 0) { s_src[n] = ss; s_dst[n] = sd; }
}

// ---------------------------------------------------------------------------
// Binscatter: LDS histogram -> reserve contiguous run in fixed-cap bucket
// region (padded global cursors, no prefix pass) -> packed scatter.
// ---------------------------------------------------------------------------
__global__ __launch_bounds__(256) void binscatter_kernel(const int* __restrict__ ei,
                                                         int* __restrict__ gcur,
                                                         unsigned* __restrict__ ebuf)
{
    __shared__ int h[NB];
    for (int i = threadIdx.x; i < NB; i += 256) h[i] = 0;
    __syncthreads();
    const int base = blockIdx.x * CHUNK;
    const int4* s4p = (const int4*)(ei + base);
    for (int i = threadIdx.x; i < CHUNK / 4; i += 256) {
        int4 s4 = s4p[i];
        atomicAdd(&h[s4.x >> BSH], 1);
        atomicAdd(&h[s4.y >> BSH], 1);
        atomicAdd(&h[s4.z >> BSH], 1);
        atomicAdd(&h[s4.w >> BSH], 1);
    }
    __syncthreads();
    for (int i = threadIdx.x; i < NB; i += 256) {
        int c = h[i];
        if (c) h[i] = i * CAP + atomicAdd(&gcur[i * 16], c);  // padded cursor line
    }
    __syncthreads();
    const int4* d4p = (const int4*)(ei + EE + base);
    for (int i = threadIdx.x; i < CHUNK / 4; i += 256) {
        int4 s4 = s4p[i];
        int4 d4 = d4p[i];
        int p0 = atomicAdd(&h[s4.x >> BSH], 1);
        int p1 = atomicAdd(&h[s4.y >> BSH], 1);
        int p2 = atomicAdd(&h[s4.z >> BSH], 1);
        int p3 = atomicAdd(&h[s4.w >> BSH], 1);
        ebuf[p0] = ((unsigned)(s4.x & (BW - 1)) << 16) | (unsigned)d4.x;
        ebuf[p1] = ((unsigned)(s4.y & (BW - 1)) << 16) | (unsigned)d4.y;
        ebuf[p2] = ((unsigned)(s4.z & (BW - 1)) << 16) | (unsigned)d4.z;
        ebuf[p3] = ((unsigned)(s4.w & (BW - 1)) << 16) | (unsigned)d4.w;
    }
}

// ---------------------------------------------------------------------------
// Fused aggregate v3: one block per 32-node bucket (1564 blocks -> ~6/CU).
//  A) register-stash edges, lane-parallel exp, LDS int histogram (32 ctrs)
//  B) wave-0 prefix scan -> node offsets; sorted LDS scatter of (d,ev)
//  C) wave x 8 nodes: lane=dim, broadcast ds_read_b64 pair, 8-deep bf16
//     row gathers, register fma; esum accumulated inline from broadcasts
//     (no strided LDS read, no shfl reduce).
// ---------------------------------------------------------------------------
__global__ __launch_bounds__(256) void aggregate_kernel(
    const unsigned* __restrict__ ebuf, const int* __restrict__ gcur,
    const ushort* __restrict__ nbuf2,
    const float* __restrict__ s_src, const float* __restrict__ s_dst,
    float* __restrict__ out)
{
    __shared__ uint2 pairs[CAP];        // {d, bits(ev)} sorted by node: 11.3 KB
    __shared__ float ssL[BW];
    __shared__ int cntL[BW], ofs[BW], cur[BW];
    const int tid  = threadIdx.x;
    const int wid  = tid >> 6;
    const int lane = tid & 63;
    const int b    = blockIdx.x;
    const int n0   = b << BSH;

    if (tid < BW) {
        int n = n0 + tid;
        ssL[tid]  = (n < NN) ? s_src[n] : 0.f;
        cntL[tid] = 0;
    }
    __syncthreads();

    const int cnt = gcur[b * 16];
    const unsigned* eb = ebuf + (size_t)b * CAP;

    unsigned er[CAPT]; float evr[CAPT];
    int nk = 0;
    for (int i = tid; i < cnt; i += 256) {        // coalesced edge load
        unsigned e = eb[i];
        int d  = e & 0xFFFFu;
        int ln = e >> 16;
        float sc = ssL[ln] + s_dst[d];            // parallel gather + exp
        float lr = sc > 0.f ? sc : SLOPE * sc;
        er[nk] = e; evr[nk] = __expf(lr); ++nk;
        atomicAdd(&cntL[ln], 1);                  // int counter only
    }
    __syncthreads();

    if (wid == 0) {                               // 32-ctr exclusive scan
        int c = (lane < BW) ? cntL[lane] : 0;
        int sc = c;
        #pragma unroll
        for (int m = 1; m < BW; m <<= 1) {
            int v = __shfl_up(sc, m, 64);
            if (lane >= m) sc += v;
        }
        if (lane < BW) { ofs[lane] = sc - c; cur[lane] = sc - c; }
    }
    __syncthreads();

    for (int k = 0; k < nk; ++k) {                // sorted LDS scatter
        int ln = er[k] >> 16;
        int pos = atomicAdd(&cur[ln], 1);
        pairs[pos] = make_uint2(er[k] & 0xFFFFu, __float_as_uint(evr[k]));
    }
    __syncthreads();

    #pragma unroll 1
    for (int t = 0; t < BW / 4; ++t) {            // wave's 8 nodes
        const int ln  = wid * (BW / 4) + t;
        const int beg = ofs[ln];
        const int len = cntL[ln];

        float acc = 0.f, es = 0.f;
        int j = 0;
        for (; j + 8 <= len; j += 8) {
            uint2 p0 = pairs[beg + j + 0], p1 = pairs[beg + j + 1];
            uint2 p2 = pairs[beg + j + 2], p3 = pairs[beg + j + 3];
            uint2 p4 = pairs[beg + j + 4], p5 = pairs[beg + j + 5];
            uint2 p6 = pairs[beg + j + 6], p7 = pairs[beg + j + 7];
            ushort u0 = nbuf2[(size_t)p0.x * OUTD + lane];
            ushort u1 = nbuf2[(size_t)p1.x * OUTD + lane];
            ushort u2 = nbuf2[(size_t)p2.x * OUTD + lane];
            ushort u3 = nbuf2[(size_t)p3.x * OUTD + lane];
            ushort u4 = nbuf2[(size_t)p4.x * OUTD + lane];
            ushort u5 = nbuf2[(size_t)p5.x * OUTD + lane];
            ushort u6 = nbuf2[(size_t)p6.x * OUTD + lane];
            ushort u7 = nbuf2[(size_t)p7.x * OUTD + lane];
            float f0 = __uint_as_float(p0.y), f1 = __uint_as_float(p1.y);
            float f2 = __uint_as_float(p2.y), f3 = __uint_as_float(p3.y);
            float f4 = __uint_as_float(p4.y), f5 = __uint_as_float(p5.y);
            float f6 = __uint_as_float(p6.y), f7 = __uint_as_float(p7.y);
            es += f0 + f1 + f2 + f3 + f4 + f5 + f6 + f7;  // inline esum
            acc = fmaf(f0, __uint_as_float((unsigned)u0 << 16), acc);
            acc = fmaf(f1, __uint_as_float((unsigned)u1 << 16), acc);
            acc = fmaf(f2, __uint_as_float((unsigned)u2 << 16), acc);
            acc = fmaf(f3, __uint_as_float((unsigned)u3 << 16), acc);
            acc = fmaf(f4, __uint_as_float((unsigned)u4 << 16), acc);
            acc = fmaf(f5, __uint_as_float((unsigned)u5 << 16), acc);
            acc = fmaf(f6, __uint_as_float((unsigned)u6 << 16), acc);
            acc = fmaf(f7, __uint_as_float((unsigned)u7 << 16), acc);
        }
        for (; j < len; ++j) {
            uint2 p = pairs[beg + j];
            ushort u = nbuf2[(size_t)p.x * OUTD + lane];
            float f = __uint_as_float(p.y);
            es += f;
            acc = fmaf(f, __uint_as_float((unsigned)u << 16), acc);
        }
        const int n = n0 + ln;
        if (n < NN)
            out[(size_t)n * OUTD + lane] = acc / (es + 1e-12f);
    }
}

// ---------------------------------------------------------------------------
extern "C" void kernel_launch(void* const* d_in, const int* in_sizes, int n_in,
                              void* d_out, int out_size, void* d_ws, size_t ws_size,
                              hipStream_t stream) {
    const float* x  = (const float*)d_in[0];
    const int*   ei = (const int*)d_in[1];    // (2,E): [0..E)=src, [E..2E)=dst
    const float* W  = (const float*)d_in[2];
    const float* b  = (const float*)d_in[3];
    const float* a  = (const float*)d_in[4];
    float* out = (float*)d_out;

    // workspace layout (~16 MB)
    ushort*   nbuf2 = (ushort*)d_ws;                      // N*64 bf16 = 6.4 MB
    float*    s_src = (float*)(nbuf2 + (size_t)NN * OUTD);// N
    float*    s_dst = s_src + NN;                         // N
    int*      gcur  = (int*)(s_dst + NN);                 // NB*16 (padded lines)
    unsigned* ebuf  = (unsigned*)(gcur + NB * 16);        // NB*CAP = 8.8 MB

    hipMemsetAsync(gcur, 0, NB * 16 * sizeof(int), stream);
    linear_kernel<<<NN / 16, 256, 0, stream>>>(x, W, b, a, nbuf2, s_src, s_dst);
    binscatter_kernel<<<NBLK, 256, 0, stream>>>(ei, gcur, ebuf);
    aggregate_kernel<<<NB, 256, 0, stream>>>(ebuf, gcur, nbuf2, s_src, s_dst, out);
}

// Round 7
// 176.532 us; speedup vs baseline: 1.2453x; 1.2453x over previous
//
#include <hip/hip_runtime.h>
#include <hip/hip_bf16.h>

#define NN    50000
#define EE    1600000
#define IND   128
#define OUTD  64
#define SLOPE 0.1f

// fine buckets (aggregate granularity)
#define BSH    5                   // log2(nodes per fine bucket)
#define BW     32                  // nodes per fine bucket
#define NB     1564                // ceil(NN / 32) aggregate blocks
#define NFINE  1568                // NC * 8 fine regions allocated
#define CAP    1408                // fine capacity: mean 1024 + 12 sigma
#define CAPT   6                   // ceil(CAP/256) register stash bound
// coarse buckets
#define CSH    8                   // log2(nodes per coarse bucket)
#define NC     196                 // ceil(NN / 256)
#define CAP1   8832                // coarse capacity: mean 8192 + 7 sigma
#define NBLK1  500
#define CHUNK1 (EE / NBLK1)        // 3200 edges per coarse block
#define NSPLIT 4
#define SCAP   (CAP1 / NSPLIT)     // 2208: deterministic stage bound

// ---------------------------------------------------------------------------
// K1: new = x @ W.T + b  (fp32 vector ALU; no fp32 MFMA on CDNA4)
//     nbuf stored bf16 (row = 128B); s_src/s_dst fp32.
// ---------------------------------------------------------------------------
__global__ __launch_bounds__(256) void linear_kernel(
    const float* __restrict__ x, const float* __restrict__ W,
    const float* __restrict__ bias, const float* __restrict__ a,
    ushort* __restrict__ nbuf2, float* __restrict__ s_src, float* __restrict__ s_dst)
{
    __shared__ float Wt[IND][OUTD + 4];   // Wt[k][j] = W[j*128+k]
    __shared__ float xs[16][IND + 4];
    const int tid = threadIdx.x;

    #pragma unroll
    for (int i = 0; i < 32; ++i) {
        int idx = tid + i * 256;          // coalesced global read of W
        Wt[idx & 127][idx >> 7] = W[idx];
    }
    const int node0 = blockIdx.x * 16;
    const float4* x4 = (const float4*)(x + (size_t)node0 * IND);
    #pragma unroll
    for (int i = 0; i < 2; ++i) {
        int idx = tid + i * 256;          // 512 float4 = 16 rows x 32
        int row = idx >> 5, col = (idx & 31) * 4;
        *(float4*)&xs[row][col] = x4[idx];
    }
    __syncthreads();

    const int nl = tid >> 4;              // local node 0..15
    const int jg = tid & 15;              // dim group
    const int j0 = jg * 4;
    float4 acc = *(const float4*)&bias[j0];
    const float* xrow = xs[nl];
    #pragma unroll
    for (int k = 0; k < IND; k += 4) {
        float4 xv = *(const float4*)&xrow[k];
        float4 w0 = *(const float4*)&Wt[k + 0][j0];
        float4 w1 = *(const float4*)&Wt[k + 1][j0];
        float4 w2 = *(const float4*)&Wt[k + 2][j0];
        float4 w3 = *(const float4*)&Wt[k + 3][j0];
        acc.x = fmaf(xv.x, w0.x, acc.x); acc.y = fmaf(xv.x, w0.y, acc.y);
        acc.z = fmaf(xv.x, w0.z, acc.z); acc.w = fmaf(xv.x, w0.w, acc.w);
        acc.x = fmaf(xv.y, w1.x, acc.x); acc.y = fmaf(xv.y, w1.y, acc.y);
        acc.z = fmaf(xv.y, w1.z, acc.z); acc.w = fmaf(xv.y, w1.w, acc.w);
        acc.x = fmaf(xv.z, w2.x, acc.x); acc.y = fmaf(xv.z, w2.y, acc.y);
        acc.z = fmaf(xv.z, w2.z, acc.z); acc.w = fmaf(xv.z, w2.w, acc.w);
        acc.x = fmaf(xv.w, w3.x, acc.x); acc.y = fmaf(xv.w, w3.y, acc.y);
        acc.z = fmaf(xv.w, w3.z, acc.z); acc.w = fmaf(xv.w, w3.w, acc.w);
    }
    const int n = node0 + nl;
    ushort4 pk;
    { __hip_bfloat16 h;
      h = __float2bfloat16(acc.x); pk.x = *(ushort*)&h;
      h = __float2bfloat16(acc.y); pk.y = *(ushort*)&h;
      h = __float2bfloat16(acc.z); pk.z = *(ushort*)&h;
      h = __float2bfloat16(acc.w); pk.w = *(ushort*)&h; }
    *(ushort4*)&nbuf2[(size_t)n * OUTD + j0] = pk;

    float ss = acc.x * a[j0]        + acc.y * a[j0 + 1]
             + acc.z * a[j0 + 2]    + acc.w * a[j0 + 3];
    float sd = acc.x * a[OUTD + j0]     + acc.y * a[OUTD + j0 + 1]
             + acc.z * a[OUTD + j0 + 2] + acc.w * a[OUTD + j0 + 3];
    #pragma unroll
    for (int m = 1; m < 16; m <<= 1) {
        ss += __shfl_xor(ss, m, 64);
        sd += __shfl_xor(sd, m, 64);
    }
    if (jg == 0) { s_src[n] = ss; s_dst[n] = sd; }
}

// ---------------------------------------------------------------------------
// Pass 1: coarse bin (196 buckets of 256 nodes). Runs ~16 edges = full 64B
// lines; 98K global atomics total. Packed (src&255)<<16 | dst (24 bits).
// ---------------------------------------------------------------------------
__global__ __launch_bounds__(256) void coarsebin_kernel(const int* __restrict__ ei,
                                                        int* __restrict__ gcur1,
                                                        unsigned* __restrict__ ebuf1)
{
    __shared__ int h[NC];
    for (int i = threadIdx.x; i < NC; i += 256) h[i] = 0;
    __syncthreads();
    const int base = blockIdx.x * CHUNK1;
    const int4* s4p = (const int4*)(ei + base);
    for (int i = threadIdx.x; i < CHUNK1 / 4; i += 256) {
        int4 s4 = s4p[i];
        atomicAdd(&h[s4.x >> CSH], 1);
        atomicAdd(&h[s4.y >> CSH], 1);
        atomicAdd(&h[s4.z >> CSH], 1);
        atomicAdd(&h[s4.w >> CSH], 1);
    }
    __syncthreads();
    for (int i = threadIdx.x; i < NC; i += 256) {
        int c = h[i];
        if (c) h[i] = i * CAP1 + atomicAdd(&gcur1[i * 16], c);
    }
    __syncthreads();
    const int4* d4p = (const int4*)(ei + EE + base);
    for (int i = threadIdx.x; i < CHUNK1 / 4; i += 256) {
        int4 s4 = s4p[i];
        int4 d4 = d4p[i];
        int p0 = atomicAdd(&h[s4.x >> CSH], 1);
        int p1 = atomicAdd(&h[s4.y >> CSH], 1);
        int p2 = atomicAdd(&h[s4.z >> CSH], 1);
        int p3 = atomicAdd(&h[s4.w >> CSH], 1);
        ebuf1[p0] = ((unsigned)(s4.x & 255) << 16) | (unsigned)d4.x;
        ebuf1[p1] = ((unsigned)(s4.y & 255) << 16) | (unsigned)d4.y;
        ebuf1[p2] = ((unsigned)(s4.z & 255) << 16) | (unsigned)d4.z;
        ebuf1[p3] = ((unsigned)(s4.w & 255) << 16) | (unsigned)d4.w;
    }
}

// ---------------------------------------------------------------------------
// Pass 2: fine bin. 4 splits per coarse bucket. LDS stage sort (deterministic
// bound SCAP), 8 global atomics/block, fully-coalesced global writes.
// ---------------------------------------------------------------------------
__global__ __launch_bounds__(256) void finebin_kernel(
    const unsigned* __restrict__ ebuf1, const int* __restrict__ gcur1,
    int* __restrict__ gcur2, unsigned* __restrict__ ebuf2)
{
    __shared__ unsigned stage[SCAP];
    __shared__ int h[8], lofs[8], grun[8], cur[8];
    const int tid = threadIdx.x;
    const int c   = blockIdx.x >> 2;
    const int sp  = blockIdx.x & 3;
    const int cnt1 = gcur1[c * 16];
    const int seg  = (cnt1 + NSPLIT - 1) / NSPLIT;
    const int lo   = sp * seg;
    const int m    = max(0, min(cnt1, lo + seg) - lo);
    if (tid < 8) h[tid] = 0;
    __syncthreads();
    const unsigned* eb = ebuf1 + (size_t)c * CAP1 + lo;
    for (int i = tid; i < m; i += 256)
        atomicAdd(&h[eb[i] >> 21], 1);          // sub = bits 21..23
    __syncthreads();
    if (tid == 0) {
        int run = 0;
        #pragma unroll
        for (int f = 0; f < 8; ++f) { lofs[f] = run; run += h[f]; }
    }
    __syncthreads();
    if (tid < 8) {
        cur[tid]  = lofs[tid];
        grun[tid] = atomicAdd(&gcur2[(c * 8 + tid) * 16], h[tid]);
    }
    __syncthreads();
    for (int i = tid; i < m; i += 256) {
        unsigned e = eb[i];
        int pos = atomicAdd(&cur[e >> 21], 1);
        stage[pos] = (((e >> 16) & 31u) << 16) | (e & 0xFFFFu);
    }
    __syncthreads();
    #pragma unroll 1
    for (int f = 0; f < 8; ++f) {
        const int cf = h[f];
        unsigned* dst = ebuf2 + (size_t)(c * 8 + f) * CAP + grun[f];
        const unsigned* sp2 = stage + lofs[f];
        for (int i = tid; i < cf; i += 256) dst[i] = sp2[i];   // coalesced
    }
}

// ---------------------------------------------------------------------------
// Fused aggregate: one block per 32-node fine bucket (1564 blocks, ~6/CU).
// Register-stash edges, lane-parallel exp, sorted LDS pair scatter, then
// per-node 8-deep bf16 row gathers with inline esum. No per-element atomics.
// ---------------------------------------------------------------------------
__global__ __launch_bounds__(256) void aggregate_kernel(
    const unsigned* __restrict__ ebuf, const int* __restrict__ gcur,
    const ushort* __restrict__ nbuf2,
    const float* __restrict__ s_src, const float* __restrict__ s_dst,
    float* __restrict__ out)
{
    __shared__ uint2 pairs[CAP];        // {d, bits(ev)} sorted by node
    __shared__ float ssL[BW];
    __shared__ int cntL[BW], ofs[BW], cur[BW];
    const int tid  = threadIdx.x;
    const int wid  = tid >> 6;
    const int lane = tid & 63;
    const int b    = blockIdx.x;
    const int n0   = b << BSH;

    if (tid < BW) {
        int n = n0 + tid;
        ssL[tid]  = (n < NN) ? s_src[n] : 0.f;
        cntL[tid] = 0;
    }
    __syncthreads();

    const int cnt = gcur[b * 16];
    const unsigned* eb = ebuf + (size_t)b * CAP;

    unsigned er[CAPT]; float evr[CAPT];
    int nk = 0;
    for (int i = tid; i < cnt; i += 256) {
        unsigned e = eb[i];
        int d  = e & 0xFFFFu;
        int ln = e >> 16;
        float sc = ssL[ln] + s_dst[d];
        float lr = sc > 0.f ? sc : SLOPE * sc;
        er[nk] = e; evr[nk] = __expf(lr); ++nk;
        atomicAdd(&cntL[ln], 1);
    }
    __syncthreads();

    if (wid == 0) {
        int c = (lane < BW) ? cntL[lane] : 0;
        int sc = c;
        #pragma unroll
        for (int m = 1; m < BW; m <<= 1) {
            int v = __shfl_up(sc, m, 64);
            if (lane >= m) sc += v;
        }
        if (lane < BW) { ofs[lane] = sc - c; cur[lane] = sc - c; }
    }
    __syncthreads();

    for (int k = 0; k < nk; ++k) {
        int ln = er[k] >> 16;
        int pos = atomicAdd(&cur[ln], 1);
        pairs[pos] = make_uint2(er[k] & 0xFFFFu, __float_as_uint(evr[k]));
    }
    __syncthreads();

    #pragma unroll 1
    for (int t = 0; t < BW / 4; ++t) {
        const int ln  = wid * (BW / 4) + t;
        const int beg = ofs[ln];
        const int len = cntL[ln];

        float acc = 0.f, es = 0.f;
        int j = 0;
        for (; j + 8 <= len; j += 8) {
            uint2 p0 = pairs[beg + j + 0], p1 = pairs[beg + j + 1];
            uint2 p2 = pairs[beg + j + 2], p3 = pairs[beg + j + 3];
            uint2 p4 = pairs[beg + j + 4], p5 = pairs[beg + j + 5];
            uint2 p6 = pairs[beg + j + 6], p7 = pairs[beg + j + 7];
            ushort u0 = nbuf2[(size_t)p0.x * OUTD + lane];
            ushort u1 = nbuf2[(size_t)p1.x * OUTD + lane];
            ushort u2 = nbuf2[(size_t)p2.x * OUTD + lane];
            ushort u3 = nbuf2[(size_t)p3.x * OUTD + lane];
            ushort u4 = nbuf2[(size_t)p4.x * OUTD + lane];
            ushort u5 = nbuf2[(size_t)p5.x * OUTD + lane];
            ushort u6 = nbuf2[(size_t)p6.x * OUTD + lane];
            ushort u7 = nbuf2[(size_t)p7.x * OUTD + lane];
            float f0 = __uint_as_float(p0.y), f1 = __uint_as_float(p1.y);
            float f2 = __uint_as_float(p2.y), f3 = __uint_as_float(p3.y);
            float f4 = __uint_as_float(p4.y), f5 = __uint_as_float(p5.y);
            float f6 = __uint_as_float(p6.y), f7 = __uint_as_float(p7.y);
            es += f0 + f1 + f2 + f3 + f4 + f5 + f6 + f7;
            acc = fmaf(f0, __uint_as_float((unsigned)u0 << 16), acc);
            acc = fmaf(f1, __uint_as_float((unsigned)u1 << 16), acc);
            acc = fmaf(f2, __uint_as_float((unsigned)u2 << 16), acc);
            acc = fmaf(f3, __uint_as_float((unsigned)u3 << 16), acc);
            acc = fmaf(f4, __uint_as_float((unsigned)u4 << 16), acc);
            acc = fmaf(f5, __uint_as_float((unsigned)u5 << 16), acc);
            acc = fmaf(f6, __uint_as_float((unsigned)u6 << 16), acc);
            acc = fmaf(f7, __uint_as_float((unsigned)u7 << 16), acc);
        }
        for (; j < len; ++j) {
            uint2 p = pairs[beg + j];
            ushort u = nbuf2[(size_t)p.x * OUTD + lane];
            float f = __uint_as_float(p.y);
            es += f;
            acc = fmaf(f, __uint_as_float((unsigned)u << 16), acc);
        }
        const int n = n0 + ln;
        if (n < NN)
            out[(size_t)n * OUTD + lane] = acc / (es + 1e-12f);
    }
}

// ---------------------------------------------------------------------------
extern "C" void kernel_launch(void* const* d_in, const int* in_sizes, int n_in,
                              void* d_out, int out_size, void* d_ws, size_t ws_size,
                              hipStream_t stream) {
    const float* x  = (const float*)d_in[0];
    const int*   ei = (const int*)d_in[1];    // (2,E): [0..E)=src, [E..2E)=dst
    const float* W  = (const float*)d_in[2];
    const float* b  = (const float*)d_in[3];
    const float* a  = (const float*)d_in[4];
    float* out = (float*)d_out;

    // workspace layout (~23 MB)
    ushort*   nbuf2 = (ushort*)d_ws;                      // N*64 bf16 = 6.4 MB
    float*    s_src = (float*)(nbuf2 + (size_t)NN * OUTD);// N
    float*    s_dst = s_src + NN;                         // N
    int*      gcur1 = (int*)(s_dst + NN);                 // NC*16
    int*      gcur2 = gcur1 + NC * 16;                    // NFINE*16
    unsigned* ebuf1 = (unsigned*)(gcur2 + NFINE * 16);    // NC*CAP1  = 6.9 MB
    unsigned* ebuf2 = ebuf1 + (size_t)NC * CAP1;          // NFINE*CAP = 8.8 MB

    hipMemsetAsync(gcur1, 0, (NC + NFINE) * 16 * sizeof(int), stream);
    linear_kernel<<<NN / 16, 256, 0, stream>>>(x, W, b, a, nbuf2, s_src, s_dst);
    coarsebin_kernel<<<NBLK1, 256, 0, stream>>>(ei, gcur1, ebuf1);
    finebin_kernel<<<NC * NSPLIT, 256, 0, stream>>>(ebuf1, gcur1, gcur2, ebuf2);
    aggregate_kernel<<<NB, 256, 0, stream>>>(ebuf2, gcur2, nbuf2, s_src, s_dst, out);
}

// Round 8
// 150.494 us; speedup vs baseline: 1.4608x; 1.1730x over previous
//
#include <hip/hip_runtime.h>
#include <hip/hip_bf16.h>

#define NN    50000
#define EE    1600000
#define IND   128
#define OUTD  64
#define SLOPE 0.1f

// fine buckets (aggregate granularity)
#define BSH    5                   // log2(nodes per fine bucket)
#define BW     32                  // nodes per fine bucket
#define NB     1564                // ceil(NN / 32) aggregate blocks
#define NFINE  1568                // NC * 8 fine regions allocated
#define CAP    1408                // fine capacity: mean 1024 + 12 sigma
#define CAPT   6                   // ceil(CAP/256) register stash bound
// coarse buckets
#define CSH    8                   // log2(nodes per coarse bucket)
#define NC     196                 // ceil(NN / 256)
#define CAP1   8832                // coarse capacity: mean 8192 + 7 sigma
#define NBLK1  500
#define CHUNK1 (EE / NBLK1)        // 3200 edges per coarse block
#define NSPLIT 4
#define SCAP   (CAP1 / NSPLIT)     // 2208: deterministic stage bound

typedef __attribute__((ext_vector_type(8))) short short8;
typedef __attribute__((ext_vector_type(4))) float float4v;

// ---------------------------------------------------------------------------
// K1 (MFMA): new = x @ W.T + b via mfma_f32_16x16x32_bf16 (fp32 accum).
// Block = 256 (4 waves) = 16 nodes. Wave w -> cols 16w..16w+15, 4 K-iters.
// LDS: x,W as bf16 (pad 8 elems/row: rows spread banks); newt fp32 tile for
// epilogue (bf16 pack + fused s_src/s_dst dot products).
// ---------------------------------------------------------------------------
__global__ __launch_bounds__(256) void linear_kernel(
    const float* __restrict__ x, const float* __restrict__ W,
    const float* __restrict__ bias, const float* __restrict__ a,
    ushort* __restrict__ nbuf2, float* __restrict__ s_src, float* __restrict__ s_dst)
{
    __shared__ ushort xs[16 * 136];     // 16 rows x (128+8) bf16
    __shared__ ushort wt[64 * 136];     // 64 rows x (128+8) bf16
    __shared__ float  newt[16 * 68];    // fp32 out tile (pad 4)
    const int tid = threadIdx.x;
    const int node0 = blockIdx.x * 16;

    // stage W (8192 floats) -> bf16 LDS
    const float4* W4 = (const float4*)W;
    #pragma unroll
    for (int i = 0; i < 8; ++i) {
        int idx = tid + i * 256;
        float4 wv = W4[idx];
        int n = idx >> 5, k = (idx & 31) * 4;
        ushort4 pk; __hip_bfloat16 h;
        h = __float2bfloat16(wv.x); pk.x = *(ushort*)&h;
        h = __float2bfloat16(wv.y); pk.y = *(ushort*)&h;
        h = __float2bfloat16(wv.z); pk.z = *(ushort*)&h;
        h = __float2bfloat16(wv.w); pk.w = *(ushort*)&h;
        *(ushort4*)&wt[n * 136 + k] = pk;
    }
    // stage x tile (2048 floats) -> bf16 LDS
    const float4* x4 = (const float4*)(x + (size_t)node0 * IND);
    #pragma unroll
    for (int i = 0; i < 2; ++i) {
        int idx = tid + i * 256;
        float4 xv = x4[idx];
        int r = idx >> 5, cc = (idx & 31) * 4;
        ushort4 pk; __hip_bfloat16 h;
        h = __float2bfloat16(xv.x); pk.x = *(ushort*)&h;
        h = __float2bfloat16(xv.y); pk.y = *(ushort*)&h;
        h = __float2bfloat16(xv.z); pk.z = *(ushort*)&h;
        h = __float2bfloat16(xv.w); pk.w = *(ushort*)&h;
        *(ushort4*)&xs[r * 136 + cc] = pk;
    }
    __syncthreads();

    const int w    = tid >> 6;
    const int lane = tid & 63;
    const int q    = lane >> 4;         // quad: k-offset q*8
    const int m16  = lane & 15;         // A row / B col
    float4v acc = {0.f, 0.f, 0.f, 0.f};
    #pragma unroll
    for (int kk = 0; kk < IND; kk += 32) {
        short8 af = *(const short8*)&xs[m16 * 136 + kk + q * 8];
        short8 bf = *(const short8*)&wt[(w * 16 + m16) * 136 + kk + q * 8];
        acc = __builtin_amdgcn_mfma_f32_16x16x32_bf16(af, bf, acc, 0, 0, 0);
    }
    const float bv = bias[w * 16 + m16];
    #pragma unroll
    for (int r = 0; r < 4; ++r)         // D: col=lane&15, row=quad*4+r
        newt[(q * 4 + r) * 68 + w * 16 + m16] = acc[r] + bv;
    __syncthreads();

    // epilogue: bf16 pack + score dots (identical structure to prior rounds)
    const int nl = tid >> 4;
    const int jg = tid & 15;
    const int j0 = jg * 4;
    float4 va = *(const float4*)&newt[nl * 68 + j0];
    const int n = node0 + nl;
    ushort4 pk;
    { __hip_bfloat16 h;
      h = __float2bfloat16(va.x); pk.x = *(ushort*)&h;
      h = __float2bfloat16(va.y); pk.y = *(ushort*)&h;
      h = __float2bfloat16(va.z); pk.z = *(ushort*)&h;
      h = __float2bfloat16(va.w); pk.w = *(ushort*)&h; }
    *(ushort4*)&nbuf2[(size_t)n * OUTD + j0] = pk;

    float ss = va.x * a[j0]        + va.y * a[j0 + 1]
             + va.z * a[j0 + 2]    + va.w * a[j0 + 3];
    float sd = va.x * a[OUTD + j0]     + va.y * a[OUTD + j0 + 1]
             + va.z * a[OUTD + j0 + 2] + va.w * a[OUTD + j0 + 3];
    #pragma unroll
    for (int m = 1; m < 16; m <<= 1) {
        ss += __shfl_xor(ss, m, 64);
        sd += __shfl_xor(sd, m, 64);
    }
    if (jg == 0) { s_src[n] = ss; s_dst[n] = sd; }
}

// ---------------------------------------------------------------------------
// Pass 1: coarse bin (196 buckets of 256 nodes). Runs ~16 edges = full 64B
// lines; 98K global atomics total. Packed (src&255)<<16 | dst (24 bits).
// ---------------------------------------------------------------------------
__global__ __launch_bounds__(256) void coarsebin_kernel(const int* __restrict__ ei,
                                                        int* __restrict__ gcur1,
                                                        unsigned* __restrict__ ebuf1)
{
    __shared__ int h[NC];
    for (int i = threadIdx.x; i < NC; i += 256) h[i] = 0;
    __syncthreads();
    const int base = blockIdx.x * CHUNK1;
    const int4* s4p = (const int4*)(ei + base);
    for (int i = threadIdx.x; i < CHUNK1 / 4; i += 256) {
        int4 s4 = s4p[i];
        atomicAdd(&h[s4.x >> CSH], 1);
        atomicAdd(&h[s4.y >> CSH], 1);
        atomicAdd(&h[s4.z >> CSH], 1);
        atomicAdd(&h[s4.w >> CSH], 1);
    }
    __syncthreads();
    for (int i = threadIdx.x; i < NC; i += 256) {
        int c = h[i];
        if (c) h[i] = i * CAP1 + atomicAdd(&gcur1[i * 16], c);
    }
    __syncthreads();
    const int4* d4p = (const int4*)(ei + EE + base);
    for (int i = threadIdx.x; i < CHUNK1 / 4; i += 256) {
        int4 s4 = s4p[i];
        int4 d4 = d4p[i];
        int p0 = atomicAdd(&h[s4.x >> CSH], 1);
        int p1 = atomicAdd(&h[s4.y >> CSH], 1);
        int p2 = atomicAdd(&h[s4.z >> CSH], 1);
        int p3 = atomicAdd(&h[s4.w >> CSH], 1);
        ebuf1[p0] = ((unsigned)(s4.x & 255) << 16) | (unsigned)d4.x;
        ebuf1[p1] = ((unsigned)(s4.y & 255) << 16) | (unsigned)d4.y;
        ebuf1[p2] = ((unsigned)(s4.z & 255) << 16) | (unsigned)d4.z;
        ebuf1[p3] = ((unsigned)(s4.w & 255) << 16) | (unsigned)d4.w;
    }
}

// ---------------------------------------------------------------------------
// Pass 2: fine bin. 4 splits per coarse bucket. LDS stage sort, 8 global
// atomics/block, fully-coalesced global writes.
// ---------------------------------------------------------------------------
__global__ __launch_bounds__(256) void finebin_kernel(
    const unsigned* __restrict__ ebuf1, const int* __restrict__ gcur1,
    int* __restrict__ gcur2, unsigned* __restrict__ ebuf2)
{
    __shared__ unsigned stage[SCAP];
    __shared__ int h[8], lofs[8], grun[8], cur[8];
    const int tid = threadIdx.x;
    const int c   = blockIdx.x >> 2;
    const int sp  = blockIdx.x & 3;
    const int cnt1 = gcur1[c * 16];
    const int seg  = (cnt1 + NSPLIT - 1) / NSPLIT;
    const int lo   = sp * seg;
    const int m    = max(0, min(cnt1, lo + seg) - lo);
    if (tid < 8) h[tid] = 0;
    __syncthreads();
    const unsigned* eb = ebuf1 + (size_t)c * CAP1 + lo;
    for (int i = tid; i < m; i += 256)
        atomicAdd(&h[eb[i] >> 21], 1);          // sub = bits 21..23
    __syncthreads();
    if (tid == 0) {
        int run = 0;
        #pragma unroll
        for (int f = 0; f < 8; ++f) { lofs[f] = run; run += h[f]; }
    }
    __syncthreads();
    if (tid < 8) {
        cur[tid]  = lofs[tid];
        grun[tid] = atomicAdd(&gcur2[(c * 8 + tid) * 16], h[tid]);
    }
    __syncthreads();
    for (int i = tid; i < m; i += 256) {
        unsigned e = eb[i];
        int pos = atomicAdd(&cur[e >> 21], 1);
        stage[pos] = (((e >> 16) & 31u) << 16) | (e & 0xFFFFu);
    }
    __syncthreads();
    #pragma unroll 1
    for (int f = 0; f < 8; ++f) {
        const int cf = h[f];
        unsigned* dst = ebuf2 + (size_t)(c * 8 + f) * CAP + grun[f];
        const unsigned* sp2 = stage + lofs[f];
        for (int i = tid; i < cf; i += 256) dst[i] = sp2[i];   // coalesced
    }
}

// ---------------------------------------------------------------------------
// Fused aggregate v4: one block per 32-node fine bucket (1564 blocks).
// Phase C: 2 edges per wave instruction — half-wave h=lane>>5 handles edge
// j+h, lane c=lane&31 gathers uint = 2 bf16 dims. Halves VMEM instr count.
// Cross-half shfl_xor(.,32) combine at node end. No per-element atomics.
// ---------------------------------------------------------------------------
__global__ __launch_bounds__(256) void aggregate_kernel(
    const unsigned* __restrict__ ebuf, const int* __restrict__ gcur,
    const ushort* __restrict__ nbuf2,
    const float* __restrict__ s_src, const float* __restrict__ s_dst,
    float* __restrict__ out)
{
    __shared__ uint2 pairs[CAP];        // {d, bits(ev)} sorted by node
    __shared__ float ssL[BW];
    __shared__ int cntL[BW], ofs[BW], cur[BW];
    const int tid  = threadIdx.x;
    const int wid  = tid >> 6;
    const int lane = tid & 63;
    const int b    = blockIdx.x;
    const int n0   = b << BSH;
    const unsigned* __restrict__ nbuf4 = (const unsigned*)nbuf2;

    if (tid < BW) {
        int n = n0 + tid;
        ssL[tid]  = (n < NN) ? s_src[n] : 0.f;
        cntL[tid] = 0;
    }
    __syncthreads();

    const int cnt = gcur[b * 16];
    const unsigned* eb = ebuf + (size_t)b * CAP;

    unsigned er[CAPT]; float evr[CAPT];
    int nk = 0;
    for (int i = tid; i < cnt; i += 256) {        // lane-parallel exp
        unsigned e = eb[i];
        int d  = e & 0xFFFFu;
        int ln = e >> 16;
        float sc = ssL[ln] + s_dst[d];
        float lr = sc > 0.f ? sc : SLOPE * sc;
        er[nk] = e; evr[nk] = __expf(lr); ++nk;
        atomicAdd(&cntL[ln], 1);
    }
    __syncthreads();

    if (wid == 0) {                               // 32-ctr exclusive scan
        int c = (lane < BW) ? cntL[lane] : 0;
        int sc = c;
        #pragma unroll
        for (int m = 1; m < BW; m <<= 1) {
            int v = __shfl_up(sc, m, 64);
            if (lane >= m) sc += v;
        }
        if (lane < BW) { ofs[lane] = sc - c; cur[lane] = sc - c; }
    }
    __syncthreads();

    for (int k = 0; k < nk; ++k) {                // sorted LDS scatter
        int ln = er[k] >> 16;
        int pos = atomicAdd(&cur[ln], 1);
        pairs[pos] = make_uint2(er[k] & 0xFFFFu, __float_as_uint(evr[k]));
    }
    __syncthreads();

    const int h32 = lane >> 5;                    // half-wave: edge parity
    const int c32 = lane & 31;                    // dim pair index

    #pragma unroll 1
    for (int t = 0; t < BW / 4; ++t) {            // wave's 8 nodes
        const int ln  = wid * (BW / 4) + t;
        const int beg = ofs[ln];
        const int len = cntL[ln];

        float accL = 0.f, accH = 0.f, es = 0.f;
        int j = 0;
        for (; j + 8 <= len; j += 8) {            // 8 edges: 4 per half
            uint2 pA = pairs[beg + j + 0 + h32];
            uint2 pB = pairs[beg + j + 2 + h32];
            uint2 pC = pairs[beg + j + 4 + h32];
            uint2 pD = pairs[beg + j + 6 + h32];
            unsigned gA = nbuf4[pA.x * 32 + c32];
            unsigned gB = nbuf4[pB.x * 32 + c32];
            unsigned gC = nbuf4[pC.x * 32 + c32];
            unsigned gD = nbuf4[pD.x * 32 + c32];
            float fA = __uint_as_float(pA.y), fB = __uint_as_float(pB.y);
            float fC = __uint_as_float(pC.y), fD = __uint_as_float(pD.y);
            es += fA + fB + fC + fD;
            accL = fmaf(fA, __uint_as_float(gA << 16), accL);
            accH = fmaf(fA, __uint_as_float(gA & 0xFFFF0000u), accH);
            accL = fmaf(fB, __uint_as_float(gB << 16), accL);
            accH = fmaf(fB, __uint_as_float(gB & 0xFFFF0000u), accH);
            accL = fmaf(fC, __uint_as_float(gC << 16), accL);
            accH = fmaf(fC, __uint_as_float(gC & 0xFFFF0000u), accH);
            accL = fmaf(fD, __uint_as_float(gD << 16), accL);
            accH = fmaf(fD, __uint_as_float(gD & 0xFFFF0000u), accH);
        }
        for (; j < len; j += 2) {                 // tail: clamp + mask
            int idx = j + h32;
            uint2 p = pairs[beg + min(idx, len - 1)];
            float f = (idx < len) ? __uint_as_float(p.y) : 0.f;
            unsigned g = nbuf4[p.x * 32 + c32];
            es += f;
            accL = fmaf(f, __uint_as_float(g << 16), accL);
            accH = fmaf(f, __uint_as_float(g & 0xFFFF0000u), accH);
        }
        es   += __shfl_xor(es, 32, 64);           // combine halves
        accL += __shfl_xor(accL, 32, 64);
        accH += __shfl_xor(accH, 32, 64);
        const int n = n0 + ln;
        if (h32 == 0 && n < NN) {
            float inv = 1.f / (es + 1e-12f);
            float2 o = make_float2(accL * inv, accH * inv);
            *(float2*)&out[(size_t)n * OUTD + 2 * c32] = o;
        }
    }
}

// ---------------------------------------------------------------------------
extern "C" void kernel_launch(void* const* d_in, const int* in_sizes, int n_in,
                              void* d_out, int out_size, void* d_ws, size_t ws_size,
                              hipStream_t stream) {
    const float* x  = (const float*)d_in[0];
    const int*   ei = (const int*)d_in[1];    // (2,E): [0..E)=src, [E..2E)=dst
    const float* W  = (const float*)d_in[2];
    const float* b  = (const float*)d_in[3];
    const float* a  = (const float*)d_in[4];
    float* out = (float*)d_out;

    // workspace layout (~23 MB)
    ushort*   nbuf2 = (ushort*)d_ws;                      // N*64 bf16 = 6.4 MB
    float*    s_src = (float*)(nbuf2 + (size_t)NN * OUTD);// N
    float*    s_dst = s_src + NN;                         // N
    int*      gcur1 = (int*)(s_dst + NN);                 // NC*16
    int*      gcur2 = gcur1 + NC * 16;                    // NFINE*16
    unsigned* ebuf1 = (unsigned*)(gcur2 + NFINE * 16);    // NC*CAP1  = 6.9 MB
    unsigned* ebuf2 = ebuf1 + (size_t)NC * CAP1;          // NFINE*CAP = 8.8 MB

    hipMemsetAsync(gcur1, 0, (NC + NFINE) * 16 * sizeof(int), stream);
    linear_kernel<<<NN / 16, 256, 0, stream>>>(x, W, b, a, nbuf2, s_src, s_dst);
    coarsebin_kernel<<<NBLK1, 256, 0, stream>>>(ei, gcur1, ebuf1);
    finebin_kernel<<<NC * NSPLIT, 256, 0, stream>>>(ebuf1, gcur1, gcur2, ebuf2);
    aggregate_kernel<<<NB, 256, 0, stream>>>(ebuf2, gcur2, nbuf2, s_src, s_dst, out);
}

// Round 9
// 146.620 us; speedup vs baseline: 1.4994x; 1.0264x over previous
//
#include <hip/hip_runtime.h>
#include <hip/hip_bf16.h>

#define NN    50000
#define EE    1600000
#define IND   128
#define OUTD  64
#define SLOPE 0.1f

// fine buckets (aggregate granularity)
#define BSH    5                   // log2(nodes per fine bucket)
#define BW     32                  // nodes per fine bucket
#define NB     1564                // ceil(NN / 32) aggregate blocks
#define NFINE  1568                // NC * 8 fine regions allocated
#define CAP    1408                // fine capacity: mean 1024 + 12 sigma
#define CAPT   6                   // ceil(CAP/256) register stash bound
// coarse buckets
#define CSH    8                   // log2(nodes per coarse bucket)
#define NC     196                 // ceil(NN / 256)
#define CAP1   8832                // coarse capacity: mean 8192 + 7 sigma
#define NBLK1  500
#define CHUNK1 (EE / NBLK1)        // 3200 edges per coarse block
#define NSPLIT 4
#define SCAP   (CAP1 / NSPLIT)     // 2208: deterministic stage bound
#define NLIN   (NN / 16)           // 3125 linear blocks

typedef __attribute__((ext_vector_type(8))) short short8;
typedef __attribute__((ext_vector_type(4))) float float4v;

// ---------------------------------------------------------------------------
// Fused K1: blocks [0,NBLK1) = coarse bin; blocks [NBLK1, NBLK1+NLIN) = MFMA
// linear. Independent workloads on different pipes (VMEM-atomic vs MFMA) —
// fusing overlaps them across CUs in one dispatch. Barriers are
// block-uniform (branch on blockIdx only).
// ---------------------------------------------------------------------------
union SMem {
    struct {
        ushort xs[16 * 136];        // x tile bf16 (pad 8/row)
        ushort wt[64 * 136];        // W bf16
        float  newt[16 * 68];       // fp32 out tile (pad 4)
    } lin;
    int h[NC];                      // coarse histogram/cursors
};

__global__ __launch_bounds__(256) void fused_lincoarse_kernel(
    const float* __restrict__ x, const float* __restrict__ W,
    const float* __restrict__ bias, const float* __restrict__ a,
    const int* __restrict__ ei, int* __restrict__ gcur1,
    unsigned* __restrict__ ebuf1,
    ushort* __restrict__ nbuf2, float* __restrict__ s_src, float* __restrict__ s_dst)
{
    __shared__ SMem sm;
    const int tid = threadIdx.x;

    if (blockIdx.x < NBLK1) {
        // ----- coarse bin: 196 buckets of 256 nodes; runs ~16 = full lines
        int* h = sm.h;
        for (int i = tid; i < NC; i += 256) h[i] = 0;
        __syncthreads();
        const int base = blockIdx.x * CHUNK1;
        const int4* s4p = (const int4*)(ei + base);
        for (int i = tid; i < CHUNK1 / 4; i += 256) {
            int4 s4 = s4p[i];
            atomicAdd(&h[s4.x >> CSH], 1);
            atomicAdd(&h[s4.y >> CSH], 1);
            atomicAdd(&h[s4.z >> CSH], 1);
            atomicAdd(&h[s4.w >> CSH], 1);
        }
        __syncthreads();
        for (int i = tid; i < NC; i += 256) {
            int c = h[i];
            if (c) h[i] = i * CAP1 + atomicAdd(&gcur1[i * 16], c);
        }
        __syncthreads();
        const int4* d4p = (const int4*)(ei + EE + base);
        for (int i = tid; i < CHUNK1 / 4; i += 256) {
            int4 s4 = s4p[i];
            int4 d4 = d4p[i];
            int p0 = atomicAdd(&h[s4.x >> CSH], 1);
            int p1 = atomicAdd(&h[s4.y >> CSH], 1);
            int p2 = atomicAdd(&h[s4.z >> CSH], 1);
            int p3 = atomicAdd(&h[s4.w >> CSH], 1);
            ebuf1[p0] = ((unsigned)(s4.x & 255) << 16) | (unsigned)d4.x;
            ebuf1[p1] = ((unsigned)(s4.y & 255) << 16) | (unsigned)d4.y;
            ebuf1[p2] = ((unsigned)(s4.z & 255) << 16) | (unsigned)d4.z;
            ebuf1[p3] = ((unsigned)(s4.w & 255) << 16) | (unsigned)d4.w;
        }
        return;
    }

    // ----- MFMA linear: new = x@W.T + b, bf16 out + fused score dots
    const int node0 = (blockIdx.x - NBLK1) * 16;
    const float4* W4 = (const float4*)W;
    #pragma unroll
    for (int i = 0; i < 8; ++i) {
        int idx = tid + i * 256;
        float4 wv = W4[idx];
        int n = idx >> 5, k = (idx & 31) * 4;
        ushort4 pk; __hip_bfloat16 h;
        h = __float2bfloat16(wv.x); pk.x = *(ushort*)&h;
        h = __float2bfloat16(wv.y); pk.y = *(ushort*)&h;
        h = __float2bfloat16(wv.z); pk.z = *(ushort*)&h;
        h = __float2bfloat16(wv.w); pk.w = *(ushort*)&h;
        *(ushort4*)&sm.lin.wt[n * 136 + k] = pk;
    }
    const float4* x4 = (const float4*)(x + (size_t)node0 * IND);
    #pragma unroll
    for (int i = 0; i < 2; ++i) {
        int idx = tid + i * 256;
        float4 xv = x4[idx];
        int r = idx >> 5, cc = (idx & 31) * 4;
        ushort4 pk; __hip_bfloat16 h;
        h = __float2bfloat16(xv.x); pk.x = *(ushort*)&h;
        h = __float2bfloat16(xv.y); pk.y = *(ushort*)&h;
        h = __float2bfloat16(xv.z); pk.z = *(ushort*)&h;
        h = __float2bfloat16(xv.w); pk.w = *(ushort*)&h;
        *(ushort4*)&sm.lin.xs[r * 136 + cc] = pk;
    }
    __syncthreads();

    const int w    = tid >> 6;
    const int lane = tid & 63;
    const int q    = lane >> 4;
    const int m16  = lane & 15;
    float4v acc = {0.f, 0.f, 0.f, 0.f};
    #pragma unroll
    for (int kk = 0; kk < IND; kk += 32) {
        short8 af = *(const short8*)&sm.lin.xs[m16 * 136 + kk + q * 8];
        short8 bf = *(const short8*)&sm.lin.wt[(w * 16 + m16) * 136 + kk + q * 8];
        acc = __builtin_amdgcn_mfma_f32_16x16x32_bf16(af, bf, acc, 0, 0, 0);
    }
    const float bv = bias[w * 16 + m16];
    #pragma unroll
    for (int r = 0; r < 4; ++r)         // D: col=lane&15, row=quad*4+r
        sm.lin.newt[(q * 4 + r) * 68 + w * 16 + m16] = acc[r] + bv;
    __syncthreads();

    const int nl = tid >> 4;
    const int jg = tid & 15;
    const int j0 = jg * 4;
    float4 va = *(const float4*)&sm.lin.newt[nl * 68 + j0];
    const int n = node0 + nl;
    ushort4 pk;
    { __hip_bfloat16 h;
      h = __float2bfloat16(va.x); pk.x = *(ushort*)&h;
      h = __float2bfloat16(va.y); pk.y = *(ushort*)&h;
      h = __float2bfloat16(va.z); pk.z = *(ushort*)&h;
      h = __float2bfloat16(va.w); pk.w = *(ushort*)&h; }
    *(ushort4*)&nbuf2[(size_t)n * OUTD + j0] = pk;

    float ss = va.x * a[j0]        + va.y * a[j0 + 1]
             + va.z * a[j0 + 2]    + va.w * a[j0 + 3];
    float sd = va.x * a[OUTD + j0]     + va.y * a[OUTD + j0 + 1]
             + va.z * a[OUTD + j0 + 2] + va.w * a[OUTD + j0 + 3];
    #pragma unroll
    for (int m = 1; m < 16; m <<= 1) {
        ss += __shfl_xor(ss, m, 64);
        sd += __shfl_xor(sd, m, 64);
    }
    if (jg == 0) { s_src[n] = ss; s_dst[n] = sd; }
}

// ---------------------------------------------------------------------------
// Pass 2: fine bin. 4 splits per coarse bucket. LDS stage sort, 8 global
// atomics/block, fully-coalesced global writes.
// ---------------------------------------------------------------------------
__global__ __launch_bounds__(256) void finebin_kernel(
    const unsigned* __restrict__ ebuf1, const int* __restrict__ gcur1,
    int* __restrict__ gcur2, unsigned* __restrict__ ebuf2)
{
    __shared__ unsigned stage[SCAP];
    __shared__ int h[8], lofs[8], grun[8], cur[8];
    const int tid = threadIdx.x;
    const int c   = blockIdx.x >> 2;
    const int sp  = blockIdx.x & 3;
    const int cnt1 = gcur1[c * 16];
    const int seg  = (cnt1 + NSPLIT - 1) / NSPLIT;
    const int lo   = sp * seg;
    const int m    = max(0, min(cnt1, lo + seg) - lo);
    if (tid < 8) h[tid] = 0;
    __syncthreads();
    const unsigned* eb = ebuf1 + (size_t)c * CAP1 + lo;
    for (int i = tid; i < m; i += 256)
        atomicAdd(&h[eb[i] >> 21], 1);          // sub = bits 21..23
    __syncthreads();
    if (tid == 0) {
        int run = 0;
        #pragma unroll
        for (int f = 0; f < 8; ++f) { lofs[f] = run; run += h[f]; }
    }
    __syncthreads();
    if (tid < 8) {
        cur[tid]  = lofs[tid];
        grun[tid] = atomicAdd(&gcur2[(c * 8 + tid) * 16], h[tid]);
    }
    __syncthreads();
    for (int i = tid; i < m; i += 256) {
        unsigned e = eb[i];
        int pos = atomicAdd(&cur[e >> 21], 1);
        stage[pos] = (((e >> 16) & 31u) << 16) | (e & 0xFFFFu);
    }
    __syncthreads();
    #pragma unroll 1
    for (int f = 0; f < 8; ++f) {
        const int cf = h[f];
        unsigned* dst = ebuf2 + (size_t)(c * 8 + f) * CAP + grun[f];
        const unsigned* sp2 = stage + lofs[f];
        for (int i = tid; i < cf; i += 256) dst[i] = sp2[i];   // coalesced
    }
}

// ---------------------------------------------------------------------------
// Fused aggregate v5: one block per 32-node fine bucket. Phase C: 4 edges
// per wave instruction — quarter-wave e16=lane>>4 handles edge j+e16; lane
// c16=lane&15 gathers uint2 = 4 bf16 dims (row = 16 lanes x 8B = 128B).
// VMEM instr count = E/4. Quarter-combine via shfl_xor(16,32) at node end.
// ---------------------------------------------------------------------------
__global__ __launch_bounds__(256) void aggregate_kernel(
    const unsigned* __restrict__ ebuf, const int* __restrict__ gcur,
    const ushort* __restrict__ nbuf2,
    const float* __restrict__ s_src, const float* __restrict__ s_dst,
    float* __restrict__ out)
{
    __shared__ uint2 pairs[CAP];        // {d, bits(ev)} sorted by node
    __shared__ float ssL[BW];
    __shared__ int cntL[BW], ofs[BW], cur[BW];
    const int tid  = threadIdx.x;
    const int wid  = tid >> 6;
    const int lane = tid & 63;
    const int b    = blockIdx.x;
    const int n0   = b << BSH;
    const uint2* __restrict__ nbufq = (const uint2*)nbuf2;  // row = 16 uint2

    if (tid < BW) {
        int n = n0 + tid;
        ssL[tid]  = (n < NN) ? s_src[n] : 0.f;
        cntL[tid] = 0;
    }
    __syncthreads();

    const int cnt = gcur[b * 16];
    const unsigned* eb = ebuf + (size_t)b * CAP;

    unsigned er[CAPT]; float evr[CAPT];
    int nk = 0;
    for (int i = tid; i < cnt; i += 256) {        // lane-parallel exp
        unsigned e = eb[i];
        int d  = e & 0xFFFFu;
        int ln = e >> 16;
        float sc = ssL[ln] + s_dst[d];
        float lr = sc > 0.f ? sc : SLOPE * sc;
        er[nk] = e; evr[nk] = __expf(lr); ++nk;
        atomicAdd(&cntL[ln], 1);
    }
    __syncthreads();

    if (wid == 0) {                               // 32-ctr exclusive scan
        int c = (lane < BW) ? cntL[lane] : 0;
        int sc = c;
        #pragma unroll
        for (int m = 1; m < BW; m <<= 1) {
            int v = __shfl_up(sc, m, 64);
            if (lane >= m) sc += v;
        }
        if (lane < BW) { ofs[lane] = sc - c; cur[lane] = sc - c; }
    }
    __syncthreads();

    for (int k = 0; k < nk; ++k) {                // sorted LDS scatter
        int ln = er[k] >> 16;
        int pos = atomicAdd(&cur[ln], 1);
        pairs[pos] = make_uint2(er[k] & 0xFFFFu, __float_as_uint(evr[k]));
    }
    __syncthreads();

    const int e16 = lane >> 4;                    // quarter: edge offset
    const int c16 = lane & 15;                    // 4-dim group (uint2)

    #pragma unroll 1
    for (int t = 0; t < BW / 4; ++t) {            // wave's 8 nodes
        const int ln  = wid * (BW / 4) + t;
        const int beg = ofs[ln];
        const int len = cntL[ln];

        float a0 = 0.f, a1 = 0.f, a2 = 0.f, a3 = 0.f, es = 0.f;
        int j = 0;
        for (; j + 16 <= len; j += 16) {          // 16 edges: 4 per quarter
            uint2 pA = pairs[beg + j + 0  + e16];
            uint2 pB = pairs[beg + j + 4  + e16];
            uint2 pC = pairs[beg + j + 8  + e16];
            uint2 pD = pairs[beg + j + 12 + e16];
            uint2 gA = nbufq[pA.x * 16 + c16];
            uint2 gB = nbufq[pB.x * 16 + c16];
            uint2 gC = nbufq[pC.x * 16 + c16];
            uint2 gD = nbufq[pD.x * 16 + c16];
            float fA = __uint_as_float(pA.y), fB = __uint_as_float(pB.y);
            float fC = __uint_as_float(pC.y), fD = __uint_as_float(pD.y);
            es += fA + fB + fC + fD;
            a0 = fmaf(fA, __uint_as_float(gA.x << 16), a0);
            a1 = fmaf(fA, __uint_as_float(gA.x & 0xFFFF0000u), a1);
            a2 = fmaf(fA, __uint_as_float(gA.y << 16), a2);
            a3 = fmaf(fA, __uint_as_float(gA.y & 0xFFFF0000u), a3);
            a0 = fmaf(fB, __uint_as_float(gB.x << 16), a0);
            a1 = fmaf(fB, __uint_as_float(gB.x & 0xFFFF0000u), a1);
            a2 = fmaf(fB, __uint_as_float(gB.y << 16), a2);
            a3 = fmaf(fB, __uint_as_float(gB.y & 0xFFFF0000u), a3);
            a0 = fmaf(fC, __uint_as_float(gC.x << 16), a0);
            a1 = fmaf(fC, __uint_as_float(gC.x & 0xFFFF0000u), a1);
            a2 = fmaf(fC, __uint_as_float(gC.y << 16), a2);
            a3 = fmaf(fC, __uint_as_float(gC.y & 0xFFFF0000u), a3);
            a0 = fmaf(fD, __uint_as_float(gD.x << 16), a0);
            a1 = fmaf(fD, __uint_as_float(gD.x & 0xFFFF0000u), a1);
            a2 = fmaf(fD, __uint_as_float(gD.y << 16), a2);
            a3 = fmaf(fD, __uint_as_float(gD.y & 0xFFFF0000u), a3);
        }
        for (; j < len; j += 4) {                 // tail: clamp + mask
            int idx = j + e16;
            uint2 p = pairs[beg + min(idx, len - 1)];
            float f = (idx < len) ? __uint_as_float(p.y) : 0.f;
            uint2 g = nbufq[p.x * 16 + c16];
            es += f;
            a0 = fmaf(f, __uint_as_float(g.x << 16), a0);
            a1 = fmaf(f, __uint_as_float(g.x & 0xFFFF0000u), a1);
            a2 = fmaf(f, __uint_as_float(g.y << 16), a2);
            a3 = fmaf(f, __uint_as_float(g.y & 0xFFFF0000u), a3);
        }
        es += __shfl_xor(es, 16, 64); es += __shfl_xor(es, 32, 64);
        a0 += __shfl_xor(a0, 16, 64); a0 += __shfl_xor(a0, 32, 64);
        a1 += __shfl_xor(a1, 16, 64); a1 += __shfl_xor(a1, 32, 64);
        a2 += __shfl_xor(a2, 16, 64); a2 += __shfl_xor(a2, 32, 64);
        a3 += __shfl_xor(a3, 16, 64); a3 += __shfl_xor(a3, 32, 64);
        const int n = n0 + ln;
        if (e16 == 0 && n < NN) {
            float inv = 1.f / (es + 1e-12f);
            float4 o = make_float4(a0 * inv, a1 * inv, a2 * inv, a3 * inv);
            *(float4*)&out[(size_t)n * OUTD + c16 * 4] = o;
        }
    }
}

// ---------------------------------------------------------------------------
extern "C" void kernel_launch(void* const* d_in, const int* in_sizes, int n_in,
                              void* d_out, int out_size, void* d_ws, size_t ws_size,
                              hipStream_t stream) {
    const float* x  = (const float*)d_in[0];
    const int*   ei = (const int*)d_in[1];    // (2,E): [0..E)=src, [E..2E)=dst
    const float* W  = (const float*)d_in[2];
    const float* b  = (const float*)d_in[3];
    const float* a  = (const float*)d_in[4];
    float* out = (float*)d_out;

    // workspace layout (~23 MB)
    ushort*   nbuf2 = (ushort*)d_ws;                      // N*64 bf16 = 6.4 MB
    float*    s_src = (float*)(nbuf2 + (size_t)NN * OUTD);// N
    float*    s_dst = s_src + NN;                         // N
    int*      gcur1 = (int*)(s_dst + NN);                 // NC*16
    int*      gcur2 = gcur1 + NC * 16;                    // NFINE*16
    unsigned* ebuf1 = (unsigned*)(gcur2 + NFINE * 16);    // NC*CAP1  = 6.9 MB
    unsigned* ebuf2 = ebuf1 + (size_t)NC * CAP1;          // NFINE*CAP = 8.8 MB

    hipMemsetAsync(gcur1, 0, (NC + NFINE) * 16 * sizeof(int), stream);
    fused_lincoarse_kernel<<<NBLK1 + NLIN, 256, 0, stream>>>(
        x, W, b, a, ei, gcur1, ebuf1, nbuf2, s_src, s_dst);
    finebin_kernel<<<NC * NSPLIT, 256, 0, stream>>>(ebuf1, gcur1, gcur2, ebuf2);
    aggregate_kernel<<<NB, 256, 0, stream>>>(ebuf2, gcur2, nbuf2, s_src, s_dst, out);
}